// Round 3
// baseline (199.734 us; speedup 1.0000x reference)
//
#include <hip/hip_runtime.h>

#define BB 32
#define HH 256
#define WW 256
#define HW (HH*WW)
#define HW4 (HW/4)
#define KP1 9
#define KNEG 8
#define MARGIN_F 10.0f
#define RATIO_INV_F 10000.0f
#define LIST_CAP 8192

// ws layout (4-byte slots):
// [0..31]    sum_pos[b]            (float)
// [32..95]   corner_sum[s][b]      (float)
// [96..159]  co_sum[s][b]          (float)
// [160..223] bo_sum[s][b]          (float)
// [224]      pos-list counter      (int)
// [256..256+LIST_CAP) list entries (int: b<<16 | pixel)

__device__ __forceinline__ float fast_tanh(float x) {
    float xc = fminf(fmaxf(x, -15.f), 15.f);
    float t = __expf(2.f * xc);
    return (t - 1.f) / (t + 1.f);
}
__device__ __forceinline__ float fast_sigmoid(float x) {
    return 1.f / (1.f + __expf(-x));
}
__device__ __forceinline__ float smooth_l1(float d) {
    float ad = fabsf(d);
    return ad < 1.f ? 0.5f * d * d : ad - 0.5f;
}
__device__ __forceinline__ float el(const float4& v, int j) {
    return reinterpret_cast<const float*>(&v)[j];
}
__device__ __forceinline__ float nlse0(float c0, float c1) {
    // log-sum-exp(c0,c1) - c0  (stable)
    const float mx = fmaxf(c0, c1);
    return mx + __logf(1.f + __expf(-fabsf(c0 - c1))) - c0;
}

// reduce one value across the block, one atomicAdd per block
__device__ __forceinline__ void block_reduce_atomic(float x, float* dst,
                                                    float* scratch) {
    const int lane = threadIdx.x & 63;
    const int wid  = threadIdx.x >> 6;
#pragma unroll
    for (int off = 32; off; off >>= 1) x += __shfl_down(x, off);
    if (lane == 0) scratch[wid] = x;
    __syncthreads();
    if (threadIdx.x == 0)
        atomicAdd(dst, scratch[0] + scratch[1] + scratch[2] + scratch[3]);
    __syncthreads();
}

// Role-split dense kernel.
// blocks [0,4096): corner-CE, s = bid>>11, per-block 1024 px (2 streams)
// blocks [4096,6144): corner-offset loss     per-block 1024 px (6 streams)
// blocks [6144,6656): t_corner scan          per-block 4096 px (1 stream)
__global__ __launch_bounds__(256) void ml_dense_kernel(
    const float* __restrict__ out0, const float* __restrict__ out1,
    const float* __restrict__ t_corner, const float* __restrict__ t_co,
    float* __restrict__ acc, int* __restrict__ wsi)
{
    __shared__ float scratch[4];
    const int bid = blockIdx.x;

    if (bid < 4096) {
        const int s = bid >> 11;
        const int r = bid & 2047;
        const int b = r >> 6, chunk = r & 63;
        const int i4 = chunk * 256 + threadIdx.x;
        const float* o = (s ? out1 : out0) + (size_t)b * 7 * HW;
        const float4 v1 = ((const float4*)(o + HW))[i4];
        const float4 v2 = ((const float4*)(o + 2 * HW))[i4];
        float sum = 0.f;
#pragma unroll
        for (int j = 0; j < 4; ++j) sum += nlse0(el(v1, j), el(v2, j));
        block_reduce_atomic(sum, &acc[32 + s * 32 + b], scratch);
    } else if (bid < 6144) {
        const int r = bid - 4096;
        const int b = r >> 6, chunk = r & 63;
        const int i4 = chunk * 256 + threadIdx.x;
        const float4* tco4 = (const float4*)(t_co + (size_t)b * 2 * HW);
        const float4* o04  = (const float4*)(out0 + (size_t)b * 7 * HW);
        const float4* o14  = (const float4*)(out1 + (size_t)b * 7 * HW);
        const float4 tg0 = tco4[i4];
        const float4 tg1 = tco4[HW4 + i4];
        const float4 a03 = o04[3 * HW4 + i4];
        const float4 a04 = o04[4 * HW4 + i4];
        const float4 a13 = o14[3 * HW4 + i4];
        const float4 a14 = o14[4 * HW4 + i4];
        float s_co0 = 0.f, s_co1 = 0.f;
#pragma unroll
        for (int j = 0; j < 4; ++j) {
            const float tgt0 = el(tg0, j), tgt1 = el(tg1, j);
            const float m0 = (tgt0 != 0.f) ? RATIO_INV_F : 1.f;
            const float m1 = (tgt1 != 0.f) ? RATIO_INV_F : 1.f;
            s_co0 += m0 * smooth_l1(fast_tanh(el(a03, j)) * (float)HH - tgt0)
                   + m1 * smooth_l1(fast_tanh(el(a04, j)) * (float)WW - tgt1);
            s_co1 += m0 * smooth_l1(fast_tanh(el(a13, j)) * (float)HH - tgt0)
                   + m1 * smooth_l1(fast_tanh(el(a14, j)) * (float)WW - tgt1);
        }
        block_reduce_atomic(s_co0, &acc[96 + b], scratch);
        block_reduce_atomic(s_co1, &acc[96 + 32 + b], scratch);
    } else {
        const int r = bid - 6144;          // 0..511, 16 blocks per batch
        const int b = r >> 4, c16 = r & 15;
        const int base4 = c16 * 1024;      // float4 index base (4096 px/block)
        const float4* tc4 = (const float4*)(t_corner + (size_t)b * HW);
        float4 v[4];
#pragma unroll
        for (int k = 0; k < 4; ++k) v[k] = tc4[base4 + k * 256 + threadIdx.x];
        float s_pos = 0.f;
#pragma unroll
        for (int k = 0; k < 4; ++k) {
#pragma unroll
            for (int j = 0; j < 4; ++j) {
                const float pv = el(v[k], j);
                if (pv != 0.f) {
                    s_pos += pv;
                    const int p = 4 * (base4 + k * 256 + threadIdx.x) + j;
                    const int idx = atomicAdd(&wsi[224], 1);
                    if (idx < LIST_CAP) wsi[256 + idx] = (b << 16) | p;
                }
            }
        }
        block_reduce_atomic(s_pos, &acc[b], scratch);
    }
}

// Sparse kernel: pos-list entries -> corner-CE pos correction + bin loss.
__global__ __launch_bounds__(256) void ml_sparse_kernel(
    const float* __restrict__ out0, const float* __restrict__ out1,
    const float* __restrict__ t_corner, const float* __restrict__ t_bin,
    float* __restrict__ acc, const int* __restrict__ wsi)
{
    const int n = min(wsi[224], LIST_CAP);
    for (int i = blockIdx.x * blockDim.x + threadIdx.x; i < n;
         i += gridDim.x * blockDim.x) {
        const int e = wsi[256 + i];
        const int b = e >> 16, p = e & 0xFFFF;
        const float pos = t_corner[(size_t)b * HW + p];
        const float tb0 = t_bin[(size_t)b * 2 * HW + p];
        const float tb1 = t_bin[(size_t)b * 2 * HW + HW + p];
#pragma unroll
        for (int s = 0; s < 2; ++s) {
            const float* o = (s ? out1 : out0) + (size_t)b * 7 * HW;
            const float c0 = o[HW + p], c1 = o[2 * HW + p];
            const float mx = fmaxf(c0, c1);
            const float lse = mx + __logf(1.f + __expf(-fabsf(c0 - c1)));
            // pos*(nl1*R) + (1-pos)*nl0 - nl0  = pos*(nl1*R - nl0)
            const float corr = pos * ((lse - c1) * RATIO_INV_F - (lse - c0));
            atomicAdd(&acc[32 + s * 32 + b], corr);
            const float sb0 = fabsf(fast_sigmoid(o[5 * HW + p]) - 0.5f - tb0);
            const float sb1 = fabsf(fast_sigmoid(o[6 * HW + p]) - 0.5f - tb1);
            atomicAdd(&acc[160 + s * 32 + b], (sb0 + sb1) * pos);
        }
    }
}

__global__ __launch_bounds__(256) void ml_final_kernel(
    const float* __restrict__ out0, const float* __restrict__ out1,
    const int* __restrict__ anchors, const int* __restrict__ positives,
    const int* __restrict__ neg_zero, const int* __restrict__ neg_other,
    const float* __restrict__ acc, float* __restrict__ out)
{
    __shared__ float lc[2];
    __shared__ float red[2][4];

    float local0 = 0.f, local1 = 0.f;
    for (int i = threadIdx.x; i < 2 * BB * KP1; i += blockDim.x) {
        const int s = i / (BB * KP1);
        const int r = i % (BB * KP1);
        const int b = r / KP1, c = r % KP1;
        const float* o = (s ? out1 : out0) + (size_t)b * 7 * HW; // channel 0
        const int ia  = anchors  [b * KP1 + c];
        const int ip  = positives[b * KP1 + c];
        const int in1 = neg_zero [b * KP1 + c];
        const float va = o[ia], vp = o[ip], vn1 = o[in1];
        const float Dap = (va - vp) * (va - vp);
        const float h1 = fmaxf(0.f, Dap - (va - vn1) * (va - vn1) + MARGIN_F);
        float pc;
        if (c > 0) {
            const int in2 = neg_other[b * KNEG + (c - 1)];
            const float vn2 = o[in2];
            const float h2 = fmaxf(0.f, Dap - (va - vn2) * (va - vn2) + MARGIN_F);
            pc = 0.5f * (h1 + h2);
        } else {
            pc = h1;
        }
        if (s == 0) local0 += pc; else local1 += pc;
    }

    const int lane = threadIdx.x & 63;
    const int wid  = threadIdx.x >> 6;
    {
        float x = local0;
#pragma unroll
        for (int off = 32; off; off >>= 1) x += __shfl_down(x, off);
        if (lane == 0) red[0][wid] = x;
    }
    {
        float x = local1;
#pragma unroll
        for (int off = 32; off; off >>= 1) x += __shfl_down(x, off);
        if (lane == 0) red[1][wid] = x;
    }
    __syncthreads();
    if (threadIdx.x < 2) {
        lc[threadIdx.x] = (red[threadIdx.x][0] + red[threadIdx.x][1] +
                           red[threadIdx.x][2] + red[threadIdx.x][3]) /
                          (float)(KP1 * BB);
    }
    __syncthreads();

    const float invHW = 1.f / (float)HW;
    for (int i = threadIdx.x; i < 2 * 97; i += blockDim.x) {
        const int s = i / 97, j = i % 97;
        float val;
        if (j == 0) {
            val = lc[s];
        } else if (j < 33) {
            const int b = j - 1;
            val = acc[32 + s * 32 + b] * invHW;            // l_corner
        } else if (j < 65) {
            const int b = j - 33;
            val = 0.25f * acc[96 + s * 32 + b] * invHW;    // l_co * LW
        } else {
            const int b = j - 65;
            const float sp = acc[b];
            val = (sp > 0.f) ? (acc[160 + s * 32 + b] / sp)
                             : (acc[160 + s * 32 + b] * invHW);
        }
        out[i] = val;
    }
}

extern "C" void kernel_launch(void* const* d_in, const int* in_sizes, int n_in,
                              void* d_out, int out_size, void* d_ws, size_t ws_size,
                              hipStream_t stream) {
    const float* out0      = (const float*)d_in[0];
    const float* out1      = (const float*)d_in[1];
    const float* t_corner  = (const float*)d_in[2];
    const float* t_co      = (const float*)d_in[3];
    const float* t_bin     = (const float*)d_in[4];
    const int*   anchors   = (const int*)d_in[5];
    const int*   positives = (const int*)d_in[6];
    const int*   neg_zero  = (const int*)d_in[7];
    const int*   neg_other = (const int*)d_in[8];
    float* acc = (float*)d_ws;
    int*   wsi = (int*)d_ws;
    float* out = (float*)d_out;

    // zero accumulators [0..223] + counter [224] (and a bit of slack)
    hipMemsetAsync(d_ws, 0, 1024, stream);

    ml_dense_kernel<<<6656, 256, 0, stream>>>(out0, out1, t_corner, t_co, acc, wsi);
    ml_sparse_kernel<<<8, 256, 0, stream>>>(out0, out1, t_corner, t_bin, acc, wsi);
    ml_final_kernel<<<1, 256, 0, stream>>>(out0, out1, anchors, positives, neg_zero,
                                           neg_other, acc, out);
}

// Round 4
// 181.699 us; speedup vs baseline: 1.0993x; 1.0993x over previous
//
#include <hip/hip_runtime.h>

#define BB 32
#define HH 256
#define WW 256
#define HW (HH*WW)
#define HW4 (HW/4)
#define KP1 9
#define KNEG 8
#define MARGIN_F 10.0f
#define RATIO_INV_F 10000.0f

// ws: 226 accumulator slots, each padded to 16 floats (64B line):
// slot 0..31     sum_pos[b]
// slot 32..95    corner_sum[s][b]   (dense nl0 sum + pos-correction)
// slot 96..159   co_sum[s][b]
// slot 160..223  bo_sum[s][b]
// slot 224..225  lc_sum[s]          (triplet-loss numerator)
#define SLOT(i) ((i)*16)
#define WS_BYTES (226*16*4)

// grid roles
#define NCE   1024                    // corner-CE:    16 blocks / (s,b) image
#define NCO   1024                    // corner-off:   32 blocks / b
#define NSCAN 128                     // t_corner scan: 4 blocks / b
#define NGATH 4                       // triplet gathers
#define GRID  (NCE + NCO + NSCAN + NGATH)

__device__ __forceinline__ float fast_tanh(float x) {
    float xc = fminf(fmaxf(x, -15.f), 15.f);
    float t = __expf(2.f * xc);
    return (t - 1.f) / (t + 1.f);
}
__device__ __forceinline__ float fast_sigmoid(float x) {
    return 1.f / (1.f + __expf(-x));
}
__device__ __forceinline__ float smooth_l1(float d) {
    float ad = fabsf(d);
    return ad < 1.f ? 0.5f * d * d : ad - 0.5f;
}
__device__ __forceinline__ float el(const float4& v, int j) {
    return reinterpret_cast<const float*>(&v)[j];
}
__device__ __forceinline__ float nlse0(float c0, float c1) {
    // log-sum-exp(c0,c1) - c0, stable
    const float mx = fmaxf(c0, c1);
    return mx + __logf(1.f + __expf(-fabsf(c0 - c1))) - c0;
}
__device__ __forceinline__ void block_reduce_atomic(float x, float* dst,
                                                    float* scratch) {
    const int lane = threadIdx.x & 63;
    const int wid  = threadIdx.x >> 6;
#pragma unroll
    for (int off = 32; off; off >>= 1) x += __shfl_down(x, off);
    __syncthreads();                 // protect scratch reuse across calls
    if (lane == 0) scratch[wid] = x;
    __syncthreads();
    if (threadIdx.x == 0)
        atomicAdd(dst, scratch[0] + scratch[1] + scratch[2] + scratch[3]);
}

__global__ __launch_bounds__(256) void ml_fused_kernel(
    const float* __restrict__ out0, const float* __restrict__ out1,
    const float* __restrict__ t_corner, const float* __restrict__ t_co,
    const float* __restrict__ t_bin,
    const int* __restrict__ anchors, const int* __restrict__ positives,
    const int* __restrict__ neg_zero, const int* __restrict__ neg_other,
    float* __restrict__ acc)
{
    __shared__ float scratch[4];
    const int bid = blockIdx.x;
    const int t = threadIdx.x;

    if (bid < NCE) {
        // ---------------- corner-CE dense: sum nl0 over all px -------------
        const int img = bid >> 4;            // 0..63  (s*32+b)
        const int s = img >> 5, b = img & 31;
        const int base = (bid & 15) * 1024;  // f4 base, 1024 f4 per block
        const float* o = (s ? out1 : out0) + (size_t)b * 7 * HW;
        const float4* c1p = (const float4*)(o + HW);
        const float4* c2p = (const float4*)(o + 2 * HW);
        float4 v1[4], v2[4];
#pragma unroll
        for (int k = 0; k < 4; ++k) v1[k] = c1p[base + k * 256 + t];
#pragma unroll
        for (int k = 0; k < 4; ++k) v2[k] = c2p[base + k * 256 + t];
        float sum = 0.f;
#pragma unroll
        for (int k = 0; k < 4; ++k)
#pragma unroll
            for (int j = 0; j < 4; ++j)
                sum += nlse0(el(v1[k], j), el(v2[k], j));
        block_reduce_atomic(sum, &acc[SLOT(32 + s * 32 + b)], scratch);

    } else if (bid < NCE + NCO) {
        // ---------------- corner-offset loss (both stacks) -----------------
        const int r = bid - NCE;
        const int b = r >> 5;
        const int base = (r & 31) * 512;     // 512 f4 per block
        const int p0 = base + t, p1 = base + 256 + t;
        const float4* tco4 = (const float4*)(t_co + (size_t)b * 2 * HW);
        const float4* o04  = (const float4*)(out0 + (size_t)b * 7 * HW);
        const float4* o14  = (const float4*)(out1 + (size_t)b * 7 * HW);
        const float4 tg0a = tco4[p0],           tg0b = tco4[p1];
        const float4 tg1a = tco4[HW4 + p0],     tg1b = tco4[HW4 + p1];
        const float4 a03a = o04[3 * HW4 + p0],  a03b = o04[3 * HW4 + p1];
        const float4 a04a = o04[4 * HW4 + p0],  a04b = o04[4 * HW4 + p1];
        const float4 a13a = o14[3 * HW4 + p0],  a13b = o14[3 * HW4 + p1];
        const float4 a14a = o14[4 * HW4 + p0],  a14b = o14[4 * HW4 + p1];
        float s0 = 0.f, s1 = 0.f;
#pragma unroll
        for (int j = 0; j < 4; ++j) {
            float tgt0 = el(tg0a, j), tgt1 = el(tg1a, j);
            float m0 = (tgt0 != 0.f) ? RATIO_INV_F : 1.f;
            float m1 = (tgt1 != 0.f) ? RATIO_INV_F : 1.f;
            s0 += m0 * smooth_l1(fast_tanh(el(a03a, j)) * (float)HH - tgt0)
                + m1 * smooth_l1(fast_tanh(el(a04a, j)) * (float)WW - tgt1);
            s1 += m0 * smooth_l1(fast_tanh(el(a13a, j)) * (float)HH - tgt0)
                + m1 * smooth_l1(fast_tanh(el(a14a, j)) * (float)WW - tgt1);
            tgt0 = el(tg0b, j); tgt1 = el(tg1b, j);
            m0 = (tgt0 != 0.f) ? RATIO_INV_F : 1.f;
            m1 = (tgt1 != 0.f) ? RATIO_INV_F : 1.f;
            s0 += m0 * smooth_l1(fast_tanh(el(a03b, j)) * (float)HH - tgt0)
                + m1 * smooth_l1(fast_tanh(el(a04b, j)) * (float)WW - tgt1);
            s1 += m0 * smooth_l1(fast_tanh(el(a13b, j)) * (float)HH - tgt0)
                + m1 * smooth_l1(fast_tanh(el(a14b, j)) * (float)WW - tgt1);
        }
        block_reduce_atomic(s0, &acc[SLOT(96 + b)], scratch);
        block_reduce_atomic(s1, &acc[SLOT(96 + 32 + b)], scratch);

    } else if (bid < NCE + NCO + NSCAN) {
        // -------- t_corner scan + inline pos-pixel corrections -------------
        const int r = bid - NCE - NCO;
        const int b = r >> 2;
        const int base = (r & 3) * 4096;     // 4096 f4 per block
        const float4* tc4 = (const float4*)(t_corner + (size_t)b * HW);
        float s_pos = 0.f;
        for (int g = 0; g < 4; ++g) {
            float4 v[4];
#pragma unroll
            for (int k = 0; k < 4; ++k) v[k] = tc4[base + (g * 4 + k) * 256 + t];
#pragma unroll
            for (int k = 0; k < 4; ++k) {
#pragma unroll
                for (int j = 0; j < 4; ++j) {
                    const float pv = el(v[k], j);
                    if (pv != 0.f) {
                        s_pos += pv;
                        const int p = 4 * (base + (g * 4 + k) * 256 + t) + j;
                        const float tb0 = t_bin[(size_t)b * 2 * HW + p];
                        const float tb1 = t_bin[(size_t)b * 2 * HW + HW + p];
#pragma unroll
                        for (int s = 0; s < 2; ++s) {
                            const float* o = (s ? out1 : out0) + (size_t)b * 7 * HW;
                            const float c0v = o[HW + p], c1v = o[2 * HW + p];
                            const float mx = fmaxf(c0v, c1v);
                            const float lse = mx + __logf(1.f + __expf(-fabsf(c0v - c1v)));
                            // pos*nl1*R + (1-pos)*nl0 - nl0 = pos*(nl1*R - nl0)
                            const float corr = pv * ((lse - c1v) * RATIO_INV_F - (lse - c0v));
                            atomicAdd(&acc[SLOT(32 + s * 32 + b)], corr);
                            const float sb0 = fabsf(fast_sigmoid(o[5 * HW + p]) - 0.5f - tb0);
                            const float sb1 = fabsf(fast_sigmoid(o[6 * HW + p]) - 0.5f - tb1);
                            atomicAdd(&acc[SLOT(160 + s * 32 + b)], (sb0 + sb1) * pv);
                        }
                    }
                }
            }
        }
        block_reduce_atomic(s_pos, &acc[SLOT(b)], scratch);

    } else {
        // ---------------- triplet gathers (l_center numerator) -------------
        const int gid = (bid - NCE - NCO - NSCAN) * 256 + t;
        float local0 = 0.f, local1 = 0.f;
        if (gid < 2 * BB * KP1) {
            const int s = gid / (BB * KP1);
            const int r = gid % (BB * KP1);
            const int b = r / KP1, c = r % KP1;
            const float* o = (s ? out1 : out0) + (size_t)b * 7 * HW;
            const int ia  = anchors  [b * KP1 + c];
            const int ip  = positives[b * KP1 + c];
            const int in1 = neg_zero [b * KP1 + c];
            const float va = o[ia], vp = o[ip], vn1 = o[in1];
            const float Dap = (va - vp) * (va - vp);
            const float h1 = fmaxf(0.f, Dap - (va - vn1) * (va - vn1) + MARGIN_F);
            float pc;
            if (c > 0) {
                const int in2 = neg_other[b * KNEG + (c - 1)];
                const float vn2 = o[in2];
                const float h2 = fmaxf(0.f, Dap - (va - vn2) * (va - vn2) + MARGIN_F);
                pc = 0.5f * (h1 + h2);
            } else {
                pc = h1;
            }
            if (s == 0) local0 = pc; else local1 = pc;
        }
        block_reduce_atomic(local0, &acc[SLOT(224)], scratch);
        block_reduce_atomic(local1, &acc[SLOT(225)], scratch);
    }
}

// Tiny finisher: reads only the 226 accumulator slots.
__global__ __launch_bounds__(256) void ml_finish_kernel(
    const float* __restrict__ acc, float* __restrict__ out)
{
    const int i = threadIdx.x;
    if (i >= 2 * 97) return;
    const int s = i / 97, j = i % 97;
    const float invHW = 1.f / (float)HW;
    float val;
    if (j == 0) {
        val = acc[SLOT(224 + s)] / (float)(KP1 * BB);
    } else if (j < 33) {
        const int b = j - 1;
        val = acc[SLOT(32 + s * 32 + b)] * invHW;            // l_corner
    } else if (j < 65) {
        const int b = j - 33;
        val = 0.25f * acc[SLOT(96 + s * 32 + b)] * invHW;    // l_co * LW
    } else {
        const int b = j - 65;
        const float sp = acc[SLOT(b)];
        val = (sp > 0.f) ? (acc[SLOT(160 + s * 32 + b)] / sp)
                         : (acc[SLOT(160 + s * 32 + b)] * invHW);
    }
    out[i] = val;
}

extern "C" void kernel_launch(void* const* d_in, const int* in_sizes, int n_in,
                              void* d_out, int out_size, void* d_ws, size_t ws_size,
                              hipStream_t stream) {
    const float* out0      = (const float*)d_in[0];
    const float* out1      = (const float*)d_in[1];
    const float* t_corner  = (const float*)d_in[2];
    const float* t_co      = (const float*)d_in[3];
    const float* t_bin     = (const float*)d_in[4];
    const int*   anchors   = (const int*)d_in[5];
    const int*   positives = (const int*)d_in[6];
    const int*   neg_zero  = (const int*)d_in[7];
    const int*   neg_other = (const int*)d_in[8];
    float* acc = (float*)d_ws;
    float* out = (float*)d_out;

    hipMemsetAsync(d_ws, 0, WS_BYTES, stream);

    ml_fused_kernel<<<GRID, 256, 0, stream>>>(out0, out1, t_corner, t_co, t_bin,
                                              anchors, positives, neg_zero,
                                              neg_other, acc);
    ml_finish_kernel<<<1, 256, 0, stream>>>(acc, out);
}

// Round 5
// 169.020 us; speedup vs baseline: 1.1817x; 1.0750x over previous
//
#include <hip/hip_runtime.h>

#define BB 32
#define HH 256
#define WW 256
#define HW (HH*WW)
#define HW4 (HW/4)
#define KP1 9
#define KNEG 8
#define MARGIN_F 10.0f
#define RATIO_INV_F 10000.0f

// ws: 226 accumulator slots, each padded to 16 floats (64B line):
// slot 0..31     sum_pos[b]
// slot 32..95    corner_sum[s][b]   (dense nl0 sum + pos-correction)
// slot 96..159   co_sum[s][b]
// slot 160..223  bo_sum[s][b]
// slot 224..225  lc_sum[s]          (triplet-loss numerator)
#define SLOT(i) ((i)*16)
#define WS_BYTES (226*16*4)

// grid roles — scan & gather FIRST (long-latency scattered work overlaps dense)
#define NSCAN 512                     // t_corner scan: 16 blocks / b, 4096 px
#define NGATH 4                       // triplet gathers
#define NCE   1024                    // corner-CE: 16 blocks / (s,b), 4096 px
#define NCO   1024                    // corner-off: 32 blocks / b, 2048 px
#define GRID  (NSCAN + NGATH + NCE + NCO)

__device__ __forceinline__ float fast_tanh(float x) {
    float xc = fminf(fmaxf(x, -15.f), 15.f);
    float t = __expf(2.f * xc);
    return (t - 1.f) / (t + 1.f);
}
__device__ __forceinline__ float fast_sigmoid(float x) {
    return 1.f / (1.f + __expf(-x));
}
__device__ __forceinline__ float smooth_l1(float d) {
    float ad = fabsf(d);
    return ad < 1.f ? 0.5f * d * d : ad - 0.5f;
}
__device__ __forceinline__ float el(const float4& v, int j) {
    return reinterpret_cast<const float*>(&v)[j];
}
__device__ __forceinline__ float nlse0(float c0, float c1) {
    const float mx = fmaxf(c0, c1);
    return mx + __logf(1.f + __expf(-fabsf(c0 - c1))) - c0;
}
__device__ __forceinline__ void block_reduce_atomic(float x, float* dst,
                                                    float* scratch) {
    const int lane = threadIdx.x & 63;
    const int wid  = threadIdx.x >> 6;
#pragma unroll
    for (int off = 32; off; off >>= 1) x += __shfl_down(x, off);
    __syncthreads();
    if (lane == 0) scratch[wid] = x;
    __syncthreads();
    if (threadIdx.x == 0)
        atomicAdd(dst, scratch[0] + scratch[1] + scratch[2] + scratch[3]);
}

__global__ __launch_bounds__(256) void ml_fused_kernel(
    const float* __restrict__ out0, const float* __restrict__ out1,
    const float* __restrict__ t_corner, const float* __restrict__ t_co,
    const float* __restrict__ t_bin,
    const int* __restrict__ anchors, const int* __restrict__ positives,
    const int* __restrict__ neg_zero, const int* __restrict__ neg_other,
    float* __restrict__ acc)
{
    __shared__ float scratch[4];
    const int bid = blockIdx.x;
    const int t = threadIdx.x;

    if (bid < NSCAN) {
        // -------- t_corner scan + inline pos-pixel corrections -------------
        const int b = bid >> 4;              // 16 blocks per batch
        const int base = (bid & 15) * 1024;  // f4 base, 4096 px per block
        const float4* tc4 = (const float4*)(t_corner + (size_t)b * HW);
        float4 v[4];
#pragma unroll
        for (int k = 0; k < 4; ++k) v[k] = tc4[base + k * 256 + t];
        float s_pos = 0.f;
#pragma unroll
        for (int k = 0; k < 4; ++k) {
#pragma unroll
            for (int j = 0; j < 4; ++j) {
                const float pv = el(v[k], j);
                if (pv != 0.f) {
                    s_pos += pv;
                    const int p = 4 * (base + k * 256 + t) + j;
                    const float* oa = out0 + (size_t)b * 7 * HW;
                    const float* ob = out1 + (size_t)b * 7 * HW;
                    // issue all 10 scattered loads as one independent batch
                    const float tb0 = t_bin[(size_t)b * 2 * HW + p];
                    const float tb1 = t_bin[(size_t)b * 2 * HW + HW + p];
                    const float a_c0 = oa[HW + p],    a_c1 = oa[2 * HW + p];
                    const float a_o5 = oa[5 * HW + p], a_o6 = oa[6 * HW + p];
                    const float b_c0 = ob[HW + p],    b_c1 = ob[2 * HW + p];
                    const float b_o5 = ob[5 * HW + p], b_o6 = ob[6 * HW + p];
                    {
                        const float mx = fmaxf(a_c0, a_c1);
                        const float lse = mx + __logf(1.f + __expf(-fabsf(a_c0 - a_c1)));
                        const float corr = pv * ((lse - a_c1) * RATIO_INV_F - (lse - a_c0));
                        atomicAdd(&acc[SLOT(32 + b)], corr);
                        const float sb0 = fabsf(fast_sigmoid(a_o5) - 0.5f - tb0);
                        const float sb1 = fabsf(fast_sigmoid(a_o6) - 0.5f - tb1);
                        atomicAdd(&acc[SLOT(160 + b)], (sb0 + sb1) * pv);
                    }
                    {
                        const float mx = fmaxf(b_c0, b_c1);
                        const float lse = mx + __logf(1.f + __expf(-fabsf(b_c0 - b_c1)));
                        const float corr = pv * ((lse - b_c1) * RATIO_INV_F - (lse - b_c0));
                        atomicAdd(&acc[SLOT(32 + 32 + b)], corr);
                        const float sb0 = fabsf(fast_sigmoid(b_o5) - 0.5f - tb0);
                        const float sb1 = fabsf(fast_sigmoid(b_o6) - 0.5f - tb1);
                        atomicAdd(&acc[SLOT(160 + 32 + b)], (sb0 + sb1) * pv);
                    }
                }
            }
        }
        block_reduce_atomic(s_pos, &acc[SLOT(b)], scratch);

    } else if (bid < NSCAN + NGATH) {
        // ---------------- triplet gathers (l_center numerator) -------------
        const int gid = (bid - NSCAN) * 256 + t;
        float local0 = 0.f, local1 = 0.f;
        if (gid < 2 * BB * KP1) {
            const int s = gid / (BB * KP1);
            const int r = gid % (BB * KP1);
            const int b = r / KP1, c = r % KP1;
            const float* o = (s ? out1 : out0) + (size_t)b * 7 * HW;
            const int ia  = anchors  [b * KP1 + c];
            const int ip  = positives[b * KP1 + c];
            const int in1 = neg_zero [b * KP1 + c];
            const float va = o[ia], vp = o[ip], vn1 = o[in1];
            const float Dap = (va - vp) * (va - vp);
            const float h1 = fmaxf(0.f, Dap - (va - vn1) * (va - vn1) + MARGIN_F);
            float pc;
            if (c > 0) {
                const int in2 = neg_other[b * KNEG + (c - 1)];
                const float vn2 = o[in2];
                const float h2 = fmaxf(0.f, Dap - (va - vn2) * (va - vn2) + MARGIN_F);
                pc = 0.5f * (h1 + h2);
            } else {
                pc = h1;
            }
            if (s == 0) local0 = pc; else local1 = pc;
        }
        block_reduce_atomic(local0, &acc[SLOT(224)], scratch);
        block_reduce_atomic(local1, &acc[SLOT(225)], scratch);

    } else if (bid < NSCAN + NGATH + NCE) {
        // ---------------- corner-CE dense: sum nl0 over all px -------------
        const int r = bid - NSCAN - NGATH;
        const int img = r >> 4;              // 0..63  (s*32+b)
        const int s = img >> 5, b = img & 31;
        const int base = (r & 15) * 1024;    // 4096 px per block
        const float* o = (s ? out1 : out0) + (size_t)b * 7 * HW;
        const float4* c1p = (const float4*)(o + HW);
        const float4* c2p = (const float4*)(o + 2 * HW);
        float4 v1[4], v2[4];
#pragma unroll
        for (int k = 0; k < 4; ++k) v1[k] = c1p[base + k * 256 + t];
#pragma unroll
        for (int k = 0; k < 4; ++k) v2[k] = c2p[base + k * 256 + t];
        float sum = 0.f;
#pragma unroll
        for (int k = 0; k < 4; ++k)
#pragma unroll
            for (int j = 0; j < 4; ++j)
                sum += nlse0(el(v1[k], j), el(v2[k], j));
        block_reduce_atomic(sum, &acc[SLOT(32 + s * 32 + b)], scratch);

    } else {
        // ---------------- corner-offset loss (both stacks) -----------------
        const int r = bid - NSCAN - NGATH - NCE;
        const int b = r >> 5;
        const int base = (r & 31) * 512;     // 2048 px per block
        const int p0 = base + t, p1 = base + 256 + t;
        const float4* tco4 = (const float4*)(t_co + (size_t)b * 2 * HW);
        const float4* o04  = (const float4*)(out0 + (size_t)b * 7 * HW);
        const float4* o14  = (const float4*)(out1 + (size_t)b * 7 * HW);
        const float4 tg0a = tco4[p0],           tg0b = tco4[p1];
        const float4 tg1a = tco4[HW4 + p0],     tg1b = tco4[HW4 + p1];
        const float4 a03a = o04[3 * HW4 + p0],  a03b = o04[3 * HW4 + p1];
        const float4 a04a = o04[4 * HW4 + p0],  a04b = o04[4 * HW4 + p1];
        const float4 a13a = o14[3 * HW4 + p0],  a13b = o14[3 * HW4 + p1];
        const float4 a14a = o14[4 * HW4 + p0],  a14b = o14[4 * HW4 + p1];
        float s0 = 0.f, s1 = 0.f;
#pragma unroll
        for (int j = 0; j < 4; ++j) {
            float tgt0 = el(tg0a, j), tgt1 = el(tg1a, j);
            float m0 = (tgt0 != 0.f) ? RATIO_INV_F : 1.f;
            float m1 = (tgt1 != 0.f) ? RATIO_INV_F : 1.f;
            s0 += m0 * smooth_l1(fast_tanh(el(a03a, j)) * (float)HH - tgt0)
                + m1 * smooth_l1(fast_tanh(el(a04a, j)) * (float)WW - tgt1);
            s1 += m0 * smooth_l1(fast_tanh(el(a13a, j)) * (float)HH - tgt0)
                + m1 * smooth_l1(fast_tanh(el(a14a, j)) * (float)WW - tgt1);
            tgt0 = el(tg0b, j); tgt1 = el(tg1b, j);
            m0 = (tgt0 != 0.f) ? RATIO_INV_F : 1.f;
            m1 = (tgt1 != 0.f) ? RATIO_INV_F : 1.f;
            s0 += m0 * smooth_l1(fast_tanh(el(a03b, j)) * (float)HH - tgt0)
                + m1 * smooth_l1(fast_tanh(el(a04b, j)) * (float)WW - tgt1);
            s1 += m0 * smooth_l1(fast_tanh(el(a13b, j)) * (float)HH - tgt0)
                + m1 * smooth_l1(fast_tanh(el(a14b, j)) * (float)WW - tgt1);
        }
        block_reduce_atomic(s0, &acc[SLOT(96 + b)], scratch);
        block_reduce_atomic(s1, &acc[SLOT(96 + 32 + b)], scratch);
    }
}

// Tiny finisher: reads only the 226 accumulator slots.
__global__ __launch_bounds__(256) void ml_finish_kernel(
    const float* __restrict__ acc, float* __restrict__ out)
{
    const int i = threadIdx.x;
    if (i >= 2 * 97) return;
    const int s = i / 97, j = i % 97;
    const float invHW = 1.f / (float)HW;
    float val;
    if (j == 0) {
        val = acc[SLOT(224 + s)] / (float)(KP1 * BB);
    } else if (j < 33) {
        const int b = j - 1;
        val = acc[SLOT(32 + s * 32 + b)] * invHW;            // l_corner
    } else if (j < 65) {
        const int b = j - 33;
        val = 0.25f * acc[SLOT(96 + s * 32 + b)] * invHW;    // l_co * LW
    } else {
        const int b = j - 65;
        const float sp = acc[SLOT(b)];
        val = (sp > 0.f) ? (acc[SLOT(160 + s * 32 + b)] / sp)
                         : (acc[SLOT(160 + s * 32 + b)] * invHW);
    }
    out[i] = val;
}

extern "C" void kernel_launch(void* const* d_in, const int* in_sizes, int n_in,
                              void* d_out, int out_size, void* d_ws, size_t ws_size,
                              hipStream_t stream) {
    const float* out0      = (const float*)d_in[0];
    const float* out1      = (const float*)d_in[1];
    const float* t_corner  = (const float*)d_in[2];
    const float* t_co      = (const float*)d_in[3];
    const float* t_bin     = (const float*)d_in[4];
    const int*   anchors   = (const int*)d_in[5];
    const int*   positives = (const int*)d_in[6];
    const int*   neg_zero  = (const int*)d_in[7];
    const int*   neg_other = (const int*)d_in[8];
    float* acc = (float*)d_ws;
    float* out = (float*)d_out;

    hipMemsetAsync(d_ws, 0, WS_BYTES, stream);

    ml_fused_kernel<<<GRID, 256, 0, stream>>>(out0, out1, t_corner, t_co, t_bin,
                                              anchors, positives, neg_zero,
                                              neg_other, acc);
    ml_finish_kernel<<<1, 256, 0, stream>>>(acc, out);
}